// Round 3
// baseline (567.581 us; speedup 1.0000x reference)
//
#include <hip/hip_runtime.h>
#include <cstdint>

typedef unsigned short u16;
typedef __attribute__((ext_vector_type(8))) short short8;
typedef __attribute__((ext_vector_type(8))) unsigned short ushort8;
typedef __attribute__((ext_vector_type(4))) float floatx4;
typedef __attribute__((ext_vector_type(8))) _Float16 half8;
typedef __attribute__((ext_vector_type(4))) unsigned uintx4;

#define S_LEN 1024
#define BATCH 64
#define EDIM 1024
#define UDIM 1024
#define VOCAB 32000
#define NTOT (3 * UDIM)        // 3072
#define CT 64                  // timesteps per scan chunk
#define NC (S_LEN / CT)        // 16 chunks

__device__ __forceinline__ u16 f2bf(float x) {
  unsigned u = __float_as_uint(x);
  return (u16)((u + 0x7fffu + ((u >> 16) & 1u)) >> 16);  // RNE, inputs are finite
}

// pack 2 f32 -> 2 bf16 in one u32 (a -> low, b -> high). No builtin on gfx950.
__device__ __forceinline__ unsigned pk_bf16(float a, float b) {
  unsigned r;
  asm("v_cvt_pk_bf16_f32 %0, %1, %2" : "=v"(r) : "v"(a), "v"(b));
  return r;
}

// async global->LDS, 16B per lane. LDS dest must be wave-uniform base + lane*16.
__device__ __forceinline__ void async16(const u16* g, u16* s) {
  __builtin_amdgcn_global_load_lds(
      (__attribute__((address_space(1))) void*)(uintptr_t)g,
      (__attribute__((address_space(3))) void*)(uintptr_t)s,
      16, 0, 0);
}

__device__ __forceinline__ float sigm(float x) {
  return __builtin_amdgcn_rcpf(1.f + __expf(-x));
}

// ------- transpose+convert W[E,U] fp32 -> Wt[U,E] bf16, 3 mats concat -------
__global__ __launch_bounds__(256) void conv_wt(const float* __restrict__ Wf,
                                               const float* __restrict__ Wi,
                                               const float* __restrict__ Wh,
                                               u16* __restrict__ wtB) {
  __shared__ float t[32][33];
  const float* W = (blockIdx.z == 0) ? Wf : ((blockIdx.z == 1) ? Wi : Wh);
  int bx = blockIdx.x * 32;  // n (input col)
  int by = blockIdx.y * 32;  // k (input row)
  int tx = threadIdx.x, ty = threadIdx.y;
  for (int j = 0; j < 32; j += 8)
    t[ty + j][tx] = W[(size_t)(by + ty + j) * UDIM + bx + tx];
  __syncthreads();
  u16* out = wtB + (size_t)blockIdx.z * UDIM * EDIM;
  for (int j = 0; j < 32; j += 8)
    out[(size_t)(bx + ty + j) * EDIM + by + tx] = f2bf(t[tx][ty + j]);
}

// ---- per-VOCAB-row gate table: 3-gate GEMM + gate nonlinearity epilogue ----
// M = 32000 = 250 m-tiles of 128 emb rows; n-tile = 64 u-cols x 3 gates.
// A (emb) consumed directly as fp32, PIPELINED (T14): fa regs for tile k+1
// are issued before the pre-MFMA barrier and stay in flight across the MFMA
// phase (counted vmcnt(8) leaves them outstanding, drains only the 6 older
// B global_load_lds). Raw s_barrier + sched_barrier fences keep the VMEM
// issue order exact so the count is sound. Round-2's serial load-cvt-write
// between __syncthreads (auto vmcnt(0)) was the 318 us regression.
// launch_bounds(256,3): acc 96 regs in AGPR + 32 held fa VGPRs; 3 blocks/CU.
__global__ __launch_bounds__(256, 3) void gate_gemm(
    const float* __restrict__ emb, const u16* __restrict__ wtB,
    const float* __restrict__ bfp, const float* __restrict__ bip,
    const float* __restrict__ bhp, u16* __restrict__ FG) {
  __shared__ __align__(16) u16 SM[128 * 64 + 192 * 64];  // 40 KB (As | Bs)
  u16* As = SM;
  u16* Bs = SM + 128 * 64;

  const int tid = threadIdx.x;
  const int wave = tid >> 6;
  const int lane = tid & 63;

  // XCD map (bijective over 4000 blocks): XCD x owns utiles {2x, 2x+1};
  // consecutive slots on an XCD share the mtile -> A fp32 fetched once into
  // that XCD's L2, twin block hits; the XCD's 2 B-slices stay L2-resident.
  const int g = blockIdx.x;
  const int x = g & 7;
  const int s = g >> 3;              // 0..499
  const int mtile = s >> 1;          // 0..249
  const int utile = x * 2 + (s & 1); // 0..15
  const int m0 = mtile * 128;
  const int u0 = utile * 64;

  // staging maps, XOR-swizzled at 16B-chunk granularity: LDS slot (row r,
  // chunk c) holds global chunk c^(r&7) -> conflict-free ds_read_b128.
  const float* gAf[4]; int loA[4];
  const u16* gB[6]; int loB[6];
#pragma unroll
  for (int j = 0; j < 4; ++j) {
    int idx = j * 256 + tid;
    int r = idx >> 3;
    int cg = (idx & 7) ^ (r & 7);
    gAf[j] = emb + (size_t)(m0 + r) * EDIM + cg * 8;  // fp32, 8 floats/chunk
    loA[j] = idx * 8;
  }
#pragma unroll
  for (int j = 0; j < 6; ++j) {
    int idx = j * 256 + tid;
    int r = idx >> 3;                            // 0..191
    int gr = (r >> 6) * UDIM + u0 + (r & 63);    // gate*1024 + u
    int cg = (idx & 7) ^ (r & 7);
    gB[j] = wtB + (size_t)gr * EDIM + cg * 8;
    loB[j] = idx * 8;
  }

  floatx4 acc[8][3] = {};
  const int fr = lane & 15;
  const int fq = lane >> 4;
  const int fr7 = fr & 7;
  const int un = wave * 16 + fr;  // u-col within block's 64

  // prologue: issue A fp32 loads for tile 0 (8 x global_load_dwordx4)
  float4 fa[8];
#pragma unroll
  for (int j = 0; j < 4; ++j) {
    fa[2 * j] = *(const float4*)(gAf[j]);
    fa[2 * j + 1] = *(const float4*)(gAf[j] + 4);
  }

  for (int k0 = 0; k0 < EDIM; k0 += 64) {
    // (1) B: async direct-to-LDS -- these 6 are the OLDEST vmem ops
#pragma unroll
    for (int j = 0; j < 6; ++j) async16(gB[j] + k0, &Bs[loB[j]]);
    __builtin_amdgcn_sched_barrier(0);
    // (2) convert previously-loaded fa -> bf16 -> LDS (implicit fa wait lands
    //     here, AFTER the B issues, so it's a counted vmcnt(6), not a drain)
#pragma unroll
    for (int j = 0; j < 4; ++j) {
      uintx4 p;
      p.x = pk_bf16(fa[2 * j].x, fa[2 * j].y);
      p.y = pk_bf16(fa[2 * j].z, fa[2 * j].w);
      p.z = pk_bf16(fa[2 * j + 1].x, fa[2 * j + 1].y);
      p.w = pk_bf16(fa[2 * j + 1].z, fa[2 * j + 1].w);
      *(short8*)&As[loA[j]] = __builtin_bit_cast(short8, p);
    }
    __builtin_amdgcn_sched_barrier(0);
    // (3) issue A loads for next tile; they stay in flight across the MFMA
    if (k0 + 64 < EDIM) {
#pragma unroll
      for (int j = 0; j < 4; ++j) {
        fa[2 * j] = *(const float4*)(gAf[j] + k0 + 64);
        fa[2 * j + 1] = *(const float4*)(gAf[j] + k0 + 64 + 4);
      }
      // 14 outstanding: wait the 6 oldest (B), keep the 8 A in flight
      asm volatile("s_waitcnt vmcnt(8) lgkmcnt(0)" ::: "memory");
    } else {
      asm volatile("s_waitcnt vmcnt(0) lgkmcnt(0)" ::: "memory");
    }
    __builtin_amdgcn_s_barrier();
    __builtin_amdgcn_sched_barrier(0);
#pragma unroll
    for (int kk = 0; kk < 2; ++kk) {
      const int swz = ((kk * 4 + fq) ^ fr7) * 8;
      short8 b0 = *(const short8*)&Bs[(0 * 64 + un) * 64 + swz];
      short8 b1 = *(const short8*)&Bs[(1 * 64 + un) * 64 + swz];
      short8 b2 = *(const short8*)&Bs[(2 * 64 + un) * 64 + swz];
#pragma unroll
      for (int mt = 0; mt < 8; ++mt) {
        short8 am = *(const short8*)&As[(mt * 16 + fr) * 64 + swz];
        acc[mt][0] = __builtin_amdgcn_mfma_f32_16x16x32_bf16(am, b0, acc[mt][0], 0, 0, 0);
        acc[mt][1] = __builtin_amdgcn_mfma_f32_16x16x32_bf16(am, b1, acc[mt][1], 0, 0, 0);
        acc[mt][2] = __builtin_amdgcn_mfma_f32_16x16x32_bf16(am, b2, acc[mt][2], 0, 0, 0);
      }
    }
    __builtin_amdgcn_sched_barrier(0);
    __builtin_amdgcn_s_barrier();   // protect LDS overwrite next iteration
    __builtin_amdgcn_sched_barrier(0);
  }

  // ---- epilogue: gate nonlinearity -> interleaved (F,G) f16 pairs ----
  // C/D layout: col=lane&15 (u), row=(lane>>4)*4+reg. row = mt*16+fq*4+r.
  // LDS restage overlays As/Bs (dead after final barrier). Pair-u32 write at
  // un ^ ((fq&1)<<4) spreads a wave's stores over all 32 banks (2-way, free).
  const int ug = u0 + un;
  const float bfv = bfp[ug], biv = bip[ug], bhv = bhp[ug];
  u16* FGs = SM;  // 128 rows x 64 pairs x u32 = 32 KB
  const int up = un ^ ((fq & 1) << 4);
#pragma unroll
  for (int mt = 0; mt < 8; ++mt) {
#pragma unroll
    for (int r = 0; r < 4; ++r) {
      float fs = sigm(acc[mt][0][r] + bfv);
      float is = sigm(acc[mt][1][r] + biv);
      float hv = acc[mt][2][r] + bhv;
      float inv = __builtin_amdgcn_rcpf(fs + is);
      float fn = fs * inv;
      float gv = is * inv * hv;
      int row = mt * 16 + fq * 4 + r;
      unsigned pkfg = (unsigned)__builtin_bit_cast(u16, (_Float16)fn) |
                      ((unsigned)__builtin_bit_cast(u16, (_Float16)gv) << 16);
      *(unsigned*)&FGs[row * 128 + up * 2] = pkfg;
    }
  }
  __syncthreads();
  // 128 rows x 16 chunks of 16B; un-group cc was written at cc ^ (fqpar<<2)
#pragma unroll
  for (int j = 0; j < 8; ++j) {
    int idx = j * 256 + tid;
    int row = idx >> 4, cc = idx & 15;
    int ccp = cc ^ (((row >> 2) & 1) << 2);
    *(ushort8*)&FG[(size_t)(m0 + row) * (2 * UDIM) + u0 * 2 + cc * 8] =
        *(const ushort8*)&FGs[row * 128 + ccp * 8];
  }
}

// ---- gather precomputed (fn, g) pairs per token + 64-step chunk scan ----
// block = (b, chunk c): 256 threads x 4 u-cols, serial over 64 timesteps.
// One 16B load per (t, thread) from the interleaved table; 8 FMA compute.
__global__ __launch_bounds__(256) void scan_gather(
    const int* __restrict__ sent, const u16* __restrict__ FG,
    float* __restrict__ Fc, float* __restrict__ Gc) {
  const int b = blockIdx.x >> 4;
  const int c = blockIdx.x & (NC - 1);
  const int tid = threadIdx.x;
  __shared__ int toks[CT];
  if (tid < CT) toks[tid] = sent[b * S_LEN + c * CT + tid];
  __syncthreads();
  const int uo2 = tid * 8;  // u16 offset within a 2048-u16 row
  floatx4 F = {1.f, 1.f, 1.f, 1.f};
  floatx4 G = {0.f, 0.f, 0.f, 0.f};
#pragma unroll 8
  for (int t = 0; t < CT; ++t) {
    const size_t ro = (size_t)toks[t] * (2 * UDIM) + uo2;
    half8 fg = __builtin_bit_cast(half8, *(const ushort8*)&FG[ro]);
    floatx4 fn = {(float)fg[0], (float)fg[2], (float)fg[4], (float)fg[6]};
    floatx4 gv = {(float)fg[1], (float)fg[3], (float)fg[5], (float)fg[7]};
    G = fn * G + gv;   // h' = fn*h + g composed left-to-right
    F = F * fn;
  }
  const size_t o = (size_t)c * (BATCH * UDIM) + (size_t)b * UDIM + tid * 4;
  *(floatx4*)&Fc[o] = F;
  *(floatx4*)&Gc[o] = G;
}

// ---------------- combine chunks + MLP head ----------------
__global__ __launch_bounds__(256) void mlp_head(
    const float* __restrict__ Fc, const float* __restrict__ Gc,
    const float* __restrict__ W1, const float* __restrict__ b1,
    const float* __restrict__ W2, const float* __restrict__ b2,
    float* __restrict__ out) {
  const int b = blockIdx.x;
  const int tid = threadIdx.x;
  __shared__ float h_s[UDIM];
  __shared__ float z1[64];
  for (int u = tid; u < UDIM; u += 256) {
    float h = 0.f;
#pragma unroll
    for (int c = 0; c < NC; ++c) {
      float F = Fc[c * (BATCH * UDIM) + b * UDIM + u];
      float G = Gc[c * (BATCH * UDIM) + b * UDIM + u];
      h = F * h + G;
    }
    h_s[u] = h;
  }
  __syncthreads();
  const int j = tid >> 2, p = tid & 3;
  float partial = 0.f;
  for (int u = p * 256; u < p * 256 + 256; ++u) partial += h_s[u] * W1[u * 64 + j];
  partial += __shfl_down(partial, 1);
  partial += __shfl_down(partial, 2);
  if (p == 0) z1[j] = partial + b1[j];
  __syncthreads();
  if (tid < 64) {
    float v = z1[tid] * W2[tid];
#pragma unroll
    for (int off = 32; off > 0; off >>= 1) v += __shfl_down(v, off);
    if (tid == 0) out[b] = 1.f / (1.f + __expf(-(v + b2[0])));
  }
}

extern "C" void kernel_launch(void* const* d_in, const int* in_sizes, int n_in,
                              void* d_out, int out_size, void* d_ws, size_t ws_size,
                              hipStream_t stream) {
  const int* sent = (const int*)d_in[0];
  const float* emb = (const float*)d_in[1];
  const float* Wf = (const float*)d_in[2];
  const float* bf_ = (const float*)d_in[3];
  const float* Wi = (const float*)d_in[4];
  const float* bi_ = (const float*)d_in[5];
  const float* Wh = (const float*)d_in[6];
  const float* bh_ = (const float*)d_in[7];
  const float* W1 = (const float*)d_in[8];
  const float* b1 = (const float*)d_in[9];
  const float* W2 = (const float*)d_in[10];
  const float* b2 = (const float*)d_in[11];
  float* out = (float*)d_out;

  // workspace layout (~146 MiB)
  char* ws = (char*)d_ws;
  u16* wtB = (u16*)ws;    ws += (size_t)NTOT * EDIM * 2;          //   6,291,456
  u16* FG = (u16*)ws;     ws += (size_t)VOCAB * UDIM * 2 * 2;     // 131,072,000
  float* Fc = (float*)ws; ws += (size_t)NC * BATCH * UDIM * 4;    //   4,194,304
  float* Gc = (float*)ws; ws += (size_t)NC * BATCH * UDIM * 4;    //   4,194,304

  hipLaunchKernelGGL(conv_wt, dim3(32, 32, 3), dim3(32, 8), 0, stream, Wf, Wi, Wh, wtB);
  hipLaunchKernelGGL(gate_gemm, dim3((VOCAB / 128) * (NTOT / 192)), dim3(256), 0, stream,
                     emb, wtB, bf_, bi_, bh_, FG);
  hipLaunchKernelGGL(scan_gather, dim3(BATCH * NC), dim3(256), 0, stream,
                     sent, FG, Fc, Gc);
  hipLaunchKernelGGL(mlp_head, dim3(BATCH), dim3(256), 0, stream, Fc, Gc, W1, b1, W2, b2, out);
}

// Round 4
// 468.894 us; speedup vs baseline: 1.2105x; 1.2105x over previous
//
#include <hip/hip_runtime.h>
#include <cstdint>

typedef unsigned short u16;
typedef __attribute__((ext_vector_type(8))) short short8;
typedef __attribute__((ext_vector_type(8))) unsigned short ushort8;
typedef __attribute__((ext_vector_type(4))) float floatx4;
typedef __attribute__((ext_vector_type(8))) _Float16 half8;

#define S_LEN 1024
#define BATCH 64
#define EDIM 1024
#define UDIM 1024
#define VOCAB 32000
#define NTOT (3 * UDIM)        // 3072
#define CT 64                  // timesteps per scan chunk
#define NC (S_LEN / CT)        // 16 chunks
#define BUFE (128 * 64 + 192 * 64)  // u16 elems per LDS K-step buffer (40 KB)

__device__ __forceinline__ u16 f2bf(float x) {
  unsigned u = __float_as_uint(x);
  return (u16)((u + 0x7fffu + ((u >> 16) & 1u)) >> 16);  // RNE, inputs are finite
}

// async global->LDS, 16B per lane. LDS dest must be wave-uniform base + lane*16.
__device__ __forceinline__ void async16(const u16* g, u16* s) {
  __builtin_amdgcn_global_load_lds(
      (__attribute__((address_space(1))) void*)(uintptr_t)g,
      (__attribute__((address_space(3))) void*)(uintptr_t)s,
      16, 0, 0);
}

__device__ __forceinline__ float sigm(float x) {
  return __builtin_amdgcn_rcpf(1.f + __expf(-x));
}

// ---------------- convert emb fp32 -> bf16 (grid-stride stream) ----------------
__global__ __launch_bounds__(256) void conv_emb(const float4* __restrict__ in,
                                                ushort4* __restrict__ out, int n4) {
  const int stride = gridDim.x * 256;
  for (int i = blockIdx.x * 256 + threadIdx.x; i < n4; i += stride) {
    float4 v = in[i];
    ushort4 o;
    o.x = f2bf(v.x); o.y = f2bf(v.y); o.z = f2bf(v.z); o.w = f2bf(v.w);
    out[i] = o;
  }
}

// ------- transpose+convert W[E,U] fp32 -> Wt[U,E] bf16, 3 mats concat -------
__global__ __launch_bounds__(256) void conv_wt(const float* __restrict__ Wf,
                                               const float* __restrict__ Wi,
                                               const float* __restrict__ Wh,
                                               u16* __restrict__ wtB) {
  __shared__ float t[32][33];
  const float* W = (blockIdx.z == 0) ? Wf : ((blockIdx.z == 1) ? Wi : Wh);
  int bx = blockIdx.x * 32;  // n (input col)
  int by = blockIdx.y * 32;  // k (input row)
  int tx = threadIdx.x, ty = threadIdx.y;
  for (int j = 0; j < 32; j += 8)
    t[ty + j][tx] = W[(size_t)(by + ty + j) * UDIM + bx + tx];
  __syncthreads();
  u16* out = wtB + (size_t)blockIdx.z * UDIM * EDIM;
  for (int j = 0; j < 32; j += 8)
    out[(size_t)(bx + ty + j) * EDIM + by + tx] = f2bf(t[tx][ty + j]);
}

// ---- per-VOCAB-row gate table: 3-gate GEMM + gate nonlinearity epilogue ----
// M = 32000 = 250 m-tiles of 128 emb rows; n-tile = 64 u-cols x 3 gates.
// R1's all-async16 staging (bf16 A from embB) restored -- R2/R3's fused fp32
// A-path lost (spills: WRITE 128->192MB, MfmaUtil 24%). New here: T3-minimum
// 2-phase LDS DOUBLE-BUFFER -- per K-step: issue 10 async16 into buf^1 FIRST,
// compute on buf (its stage drained last iter), then ONE vmcnt(0)+s_barrier.
// The stage gets the whole 48-MFMA phase to land instead of being drained
// immediately by __syncthreads' vmcnt(0). LDS 80KB -> 2 blocks/CU.
__global__ __launch_bounds__(256, 2) void gate_gemm(
    const u16* __restrict__ embB, const u16* __restrict__ wtB,
    const float* __restrict__ bfp, const float* __restrict__ bip,
    const float* __restrict__ bhp, u16* __restrict__ FG) {
  __shared__ __align__(16) u16 SM[2 * BUFE];  // 80 KB, double-buffered (A|B)

  const int tid = threadIdx.x;
  const int wave = tid >> 6;
  const int lane = tid & 63;

  // XCD map (bijective over 4000 blocks): XCD x owns utiles {2x, 2x+1};
  // consecutive slots on an XCD share the mtile -> A fetched once into that
  // XCD's L2, twin block hits; the XCD's 2 B-slices stay L2-resident.
  const int g = blockIdx.x;
  const int x = g & 7;
  const int s = g >> 3;              // 0..499
  const int mtile = s >> 1;          // 0..249
  const int utile = x * 2 + (s & 1); // 0..15
  const int m0 = mtile * 128;
  const int u0 = utile * 64;

  // staging maps, XOR-swizzled at 16B-chunk granularity: LDS slot (row r,
  // chunk c) holds global chunk c^(r&7) -> conflict-free ds_read_b128.
  const u16* gA[4]; int loA[4];
  const u16* gB[6]; int loB[6];
#pragma unroll
  for (int j = 0; j < 4; ++j) {
    int idx = j * 256 + tid;
    int r = idx >> 3;
    int cg = (idx & 7) ^ (r & 7);
    gA[j] = embB + (size_t)(m0 + r) * EDIM + cg * 8;
    loA[j] = idx * 8;
  }
#pragma unroll
  for (int j = 0; j < 6; ++j) {
    int idx = j * 256 + tid;
    int r = idx >> 3;                            // 0..191
    int gr = (r >> 6) * UDIM + u0 + (r & 63);    // gate*1024 + u
    int cg = (idx & 7) ^ (r & 7);
    gB[j] = wtB + (size_t)gr * EDIM + cg * 8;
    loB[j] = 128 * 64 + idx * 8;                 // B region within a buffer
  }

  floatx4 acc[8][3] = {};
  const int fr = lane & 15;
  const int fq = lane >> 4;
  const int fr7 = fr & 7;
  const int un = wave * 16 + fr;  // u-col within block's 64

  // prologue: stage tile 0 into buf0, drain, barrier
#pragma unroll
  for (int j = 0; j < 4; ++j) async16(gA[j], &SM[loA[j]]);
#pragma unroll
  for (int j = 0; j < 6; ++j) async16(gB[j], &SM[loB[j]]);
  asm volatile("s_waitcnt vmcnt(0)" ::: "memory");
  __builtin_amdgcn_s_barrier();
  __builtin_amdgcn_sched_barrier(0);

  int cur = 0;
  for (int t = 0; t < EDIM / 64; ++t) {
    // (1) issue next tile's stage into the other buffer (no one reads it:
    //     its readers finished before last iteration's end barrier)
    if (t + 1 < EDIM / 64) {
      const int k0 = (t + 1) * 64;
      u16* nb = SM + (cur ^ 1) * BUFE;
#pragma unroll
      for (int j = 0; j < 4; ++j) async16(gA[j] + k0, &nb[loA[j]]);
#pragma unroll
      for (int j = 0; j < 6; ++j) async16(gB[j] + k0, &nb[loB[j]]);
    }
    __builtin_amdgcn_sched_barrier(0);
    // (2) compute on current buffer (staged last iter, drained at its end)
    const u16* As = SM + cur * BUFE;
    const u16* Bs = As + 128 * 64;
#pragma unroll
    for (int kk = 0; kk < 2; ++kk) {
      const int swz = ((kk * 4 + fq) ^ fr7) * 8;
      short8 b0 = *(const short8*)&Bs[(0 * 64 + un) * 64 + swz];
      short8 b1 = *(const short8*)&Bs[(1 * 64 + un) * 64 + swz];
      short8 b2 = *(const short8*)&Bs[(2 * 64 + un) * 64 + swz];
#pragma unroll
      for (int mt = 0; mt < 8; ++mt) {
        short8 am = *(const short8*)&As[(mt * 16 + fr) * 64 + swz];
        acc[mt][0] = __builtin_amdgcn_mfma_f32_16x16x32_bf16(am, b0, acc[mt][0], 0, 0, 0);
        acc[mt][1] = __builtin_amdgcn_mfma_f32_16x16x32_bf16(am, b1, acc[mt][1], 0, 0, 0);
        acc[mt][2] = __builtin_amdgcn_mfma_f32_16x16x32_bf16(am, b2, acc[mt][2], 0, 0, 0);
      }
    }
    __builtin_amdgcn_sched_barrier(0);
    // (3) drain this iteration's stage (had the whole MFMA phase to fly),
    //     one barrier per tile
    asm volatile("s_waitcnt vmcnt(0)" ::: "memory");
    __builtin_amdgcn_s_barrier();
    __builtin_amdgcn_sched_barrier(0);
    cur ^= 1;
  }

  // ---- epilogue: gate nonlinearity -> interleaved (F,G) f16 pairs ----
  // C/D layout: col=lane&15 (u), row=(lane>>4)*4+reg. row = mt*16+fq*4+r.
  // LDS restage overlays buf0 (dead after final barrier). Pair-u32 write at
  // un ^ ((fq&1)<<4) spreads a wave's stores over all 32 banks (2-way, free).
  const int ug = u0 + un;
  const float bfv = bfp[ug], biv = bip[ug], bhv = bhp[ug];
  u16* FGs = SM;  // 128 rows x 64 pairs x u32 = 32 KB
  const int up = un ^ ((fq & 1) << 4);
#pragma unroll
  for (int mt = 0; mt < 8; ++mt) {
#pragma unroll
    for (int r = 0; r < 4; ++r) {
      float fs = sigm(acc[mt][0][r] + bfv);
      float is = sigm(acc[mt][1][r] + biv);
      float hv = acc[mt][2][r] + bhv;
      float inv = __builtin_amdgcn_rcpf(fs + is);
      float fn = fs * inv;
      float gv = is * inv * hv;
      int row = mt * 16 + fq * 4 + r;
      unsigned pkfg = (unsigned)__builtin_bit_cast(u16, (_Float16)fn) |
                      ((unsigned)__builtin_bit_cast(u16, (_Float16)gv) << 16);
      *(unsigned*)&FGs[row * 128 + up * 2] = pkfg;
    }
  }
  __syncthreads();
  // 128 rows x 16 chunks of 16B; un-group cc was written at cc ^ (fqpar<<2)
#pragma unroll
  for (int j = 0; j < 8; ++j) {
    int idx = j * 256 + tid;
    int row = idx >> 4, cc = idx & 15;
    int ccp = cc ^ (((row >> 2) & 1) << 2);
    *(ushort8*)&FG[(size_t)(m0 + row) * (2 * UDIM) + u0 * 2 + cc * 8] =
        *(const ushort8*)&FGs[row * 128 + ccp * 8];
  }
}

// ---- gather precomputed (fn, g) pairs per token + 64-step chunk scan ----
// block = (b, chunk c): 256 threads x 4 u-cols, serial over 64 timesteps.
// One 16B load per (t, thread) from the interleaved table; 8 FMA compute.
__global__ __launch_bounds__(256) void scan_gather(
    const int* __restrict__ sent, const u16* __restrict__ FG,
    float* __restrict__ Fc, float* __restrict__ Gc) {
  const int b = blockIdx.x >> 4;
  const int c = blockIdx.x & (NC - 1);
  const int tid = threadIdx.x;
  __shared__ int toks[CT];
  if (tid < CT) toks[tid] = sent[b * S_LEN + c * CT + tid];
  __syncthreads();
  const int uo2 = tid * 8;  // u16 offset within a 2048-u16 row
  floatx4 F = {1.f, 1.f, 1.f, 1.f};
  floatx4 G = {0.f, 0.f, 0.f, 0.f};
#pragma unroll 8
  for (int t = 0; t < CT; ++t) {
    const size_t ro = (size_t)toks[t] * (2 * UDIM) + uo2;
    half8 fg = __builtin_bit_cast(half8, *(const ushort8*)&FG[ro]);
    floatx4 fn = {(float)fg[0], (float)fg[2], (float)fg[4], (float)fg[6]};
    floatx4 gv = {(float)fg[1], (float)fg[3], (float)fg[5], (float)fg[7]};
    G = fn * G + gv;   // h' = fn*h + g composed left-to-right
    F = F * fn;
  }
  const size_t o = (size_t)c * (BATCH * UDIM) + (size_t)b * UDIM + tid * 4;
  *(floatx4*)&Fc[o] = F;
  *(floatx4*)&Gc[o] = G;
}

// ---------------- combine chunks + MLP head ----------------
__global__ __launch_bounds__(256) void mlp_head(
    const float* __restrict__ Fc, const float* __restrict__ Gc,
    const float* __restrict__ W1, const float* __restrict__ b1,
    const float* __restrict__ W2, const float* __restrict__ b2,
    float* __restrict__ out) {
  const int b = blockIdx.x;
  const int tid = threadIdx.x;
  __shared__ float h_s[UDIM];
  __shared__ float z1[64];
  for (int u = tid; u < UDIM; u += 256) {
    float h = 0.f;
#pragma unroll
    for (int c = 0; c < NC; ++c) {
      float F = Fc[c * (BATCH * UDIM) + b * UDIM + u];
      float G = Gc[c * (BATCH * UDIM) + b * UDIM + u];
      h = F * h + G;
    }
    h_s[u] = h;
  }
  __syncthreads();
  const int j = tid >> 2, p = tid & 3;
  float partial = 0.f;
  for (int u = p * 256; u < p * 256 + 256; ++u) partial += h_s[u] * W1[u * 64 + j];
  partial += __shfl_down(partial, 1);
  partial += __shfl_down(partial, 2);
  if (p == 0) z1[j] = partial + b1[j];
  __syncthreads();
  if (tid < 64) {
    float v = z1[tid] * W2[tid];
#pragma unroll
    for (int off = 32; off > 0; off >>= 1) v += __shfl_down(v, off);
    if (tid == 0) out[b] = 1.f / (1.f + __expf(-(v + b2[0])));
  }
}

extern "C" void kernel_launch(void* const* d_in, const int* in_sizes, int n_in,
                              void* d_out, int out_size, void* d_ws, size_t ws_size,
                              hipStream_t stream) {
  const int* sent = (const int*)d_in[0];
  const float* emb = (const float*)d_in[1];
  const float* Wf = (const float*)d_in[2];
  const float* bf_ = (const float*)d_in[3];
  const float* Wi = (const float*)d_in[4];
  const float* bi_ = (const float*)d_in[5];
  const float* Wh = (const float*)d_in[6];
  const float* bh_ = (const float*)d_in[7];
  const float* W1 = (const float*)d_in[8];
  const float* b1 = (const float*)d_in[9];
  const float* W2 = (const float*)d_in[10];
  const float* b2 = (const float*)d_in[11];
  float* out = (float*)d_out;

  // workspace layout (~207 MiB)
  char* ws = (char*)d_ws;
  u16* embB = (u16*)ws;   ws += (size_t)VOCAB * EDIM * 2;         //  65,536,000
  u16* wtB = (u16*)ws;    ws += (size_t)NTOT * EDIM * 2;          //   6,291,456
  u16* FG = (u16*)ws;     ws += (size_t)VOCAB * UDIM * 2 * 2;     // 131,072,000
  float* Fc = (float*)ws; ws += (size_t)NC * BATCH * UDIM * 4;    //   4,194,304
  float* Gc = (float*)ws; ws += (size_t)NC * BATCH * UDIM * 4;    //   4,194,304

  int n4 = (int)((size_t)VOCAB * EDIM / 4);
  hipLaunchKernelGGL(conv_emb, dim3(2048), dim3(256), 0, stream,
                     (const float4*)emb, (ushort4*)embB, n4);
  hipLaunchKernelGGL(conv_wt, dim3(32, 32, 3), dim3(32, 8), 0, stream, Wf, Wi, Wh, wtB);
  hipLaunchKernelGGL(gate_gemm, dim3((VOCAB / 128) * (NTOT / 192)), dim3(256), 0, stream,
                     embB, wtB, bf_, bi_, bh_, FG);
  hipLaunchKernelGGL(scan_gather, dim3(BATCH * NC), dim3(256), 0, stream,
                     sent, FG, Fc, Gc);
  hipLaunchKernelGGL(mlp_head, dim3(BATCH), dim3(256), 0, stream, Fc, Gc, W1, b1, W2, b2, out);
}